// Round 1
// baseline (864.369 us; speedup 1.0000x reference)
//
#include <hip/hip_runtime.h>
#include <hip/hip_bf16.h>
#include <hip/hip_fp16.h>

// DLRM small: B=16384, VOCAB=2^20, EMBED=128
// bottom MLP 13->512->256->128 (relu), interaction (27x27 triu incl diag),
// top MLP 506->1024->1024->512->256->1 (relu except last).
//
// Strategy: fp16 MFMA (16x16x32) for all matmuls, fp32 accumulate.
// Weights transposed+converted to fp16 [N][Kpad] per launch (ws re-poisoned).

#define BROWS 16384
#define VOCAB_MASK 1048575

typedef __attribute__((ext_vector_type(8))) _Float16 half8;
typedef __attribute__((ext_vector_type(4))) float f32x4;

__device__ __forceinline__ void gld16(const void* g, void* l) {
  __builtin_amdgcn_global_load_lds(
      (const __attribute__((address_space(1))) void*)g,
      (__attribute__((address_space(3))) void*)l, 16, 0, 0);
}

__device__ __forceinline__ f32x4 mfma_f16(half8 a, half8 b, f32x4 c) {
  return __builtin_amdgcn_mfma_f32_16x16x32_f16(a, b, c, 0, 0, 0);
}

// ---------------------------------------------------------------------------
// Transpose + convert: src fp32 [K][N] -> dst fp16 [N][Kp], zero pad k in [K,Kp)
__global__ __launch_bounds__(256) void transpose_to_f16(
    const float* __restrict__ src, _Float16* __restrict__ dst,
    int K, int N, int Kp) {
  __shared__ float tile[32][33];
  int kb = blockIdx.y * 32, nb = blockIdx.x * 32;
  int tx = threadIdx.x, ty = threadIdx.y;  // 32 x 8
  #pragma unroll
  for (int i = 0; i < 32; i += 8) {
    int k = kb + ty + i, n = nb + tx;
    tile[ty + i][tx] = (k < K && n < N) ? src[(size_t)k * N + n] : 0.f;
  }
  __syncthreads();
  #pragma unroll
  for (int i = 0; i < 32; i += 8) {
    int n = nb + ty + i, k = kb + tx;
    if (n < N && k < Kp) dst[(size_t)n * Kp + k] = (_Float16)tile[tx][ty + i];
  }
}

// ---------------------------------------------------------------------------
// Build dense input fp16 [B][32] (cols 13..31 zero) from x fp32 [B][39]
__global__ __launch_bounds__(256) void build_dense(
    const float* __restrict__ x, _Float16* __restrict__ d) {
  int i = blockIdx.x * 256 + threadIdx.x;
  int b = i >> 5, c = i & 31;
  d[i] = (c < 13) ? (_Float16)x[(size_t)b * 39 + c] : (_Float16)0.f;
}

// ---------------------------------------------------------------------------
// GEMM: C[M][N] = act(A[M][K] * Bt[N][K]^T + bias), fp16 in/out, fp32 acc.
// m97 structure: 128x128 tile, BK=32, 4 waves, 4x4 16x16x32 fragments/wave.
// M%128==0, N%128==0, K%32==0 required.
template <int RELU>
__global__ __launch_bounds__(256) void gemm_bt(
    const _Float16* __restrict__ A, const _Float16* __restrict__ Bt,
    const float* __restrict__ bias, _Float16* __restrict__ C,
    int M, int N, int K) {
  __shared__ __align__(16) _Float16 As[128 * 32];
  __shared__ __align__(16) _Float16 Bs[128 * 32];
  int tid = threadIdx.x, wv = tid >> 6, lane = tid & 63;
  int m0 = blockIdx.x * 128, n0 = blockIdx.y * 128;
  int wm = (wv & 1) * 64, wn = (wv >> 1) * 64;
  int lm = lane & 15, q = lane >> 4;

  f32x4 zero = {0.f, 0.f, 0.f, 0.f};
  f32x4 acc[4][4];
  #pragma unroll
  for (int i = 0; i < 4; i++)
    #pragma unroll
    for (int j = 0; j < 4; j++) acc[i][j] = zero;

  int c0 = tid, c1 = tid + 256;                 // 16B chunks: row=c>>2, off=(c&3)*8
  int r0 = c0 >> 2, o0 = (c0 & 3) * 8;
  int r1 = c1 >> 2, o1 = (c1 & 3) * 8;

  for (int kk = 0; kk < K; kk += 32) {
    __syncthreads();  // previous iteration's readers done
    gld16(A + (size_t)(m0 + r0) * K + kk + o0, &As[c0 * 8]);
    gld16(A + (size_t)(m0 + r1) * K + kk + o1, &As[c1 * 8]);
    gld16(Bt + (size_t)(n0 + r0) * K + kk + o0, &Bs[c0 * 8]);
    gld16(Bt + (size_t)(n0 + r1) * K + kk + o1, &Bs[c1 * 8]);
    __syncthreads();  // drains vmcnt(0) before barrier -> tiles ready

    half8 af[4], bf[4];
    #pragma unroll
    for (int i = 0; i < 4; i++)
      af[i] = *(const half8*)&As[(wm + i * 16 + lm) * 32 + q * 8];
    #pragma unroll
    for (int i = 0; i < 4; i++)
      bf[i] = *(const half8*)&Bs[(wn + i * 16 + lm) * 32 + q * 8];
    #pragma unroll
    for (int mi = 0; mi < 4; mi++)
      #pragma unroll
      for (int ni = 0; ni < 4; ni++)
        acc[mi][ni] = mfma_f16(af[mi], bf[ni], acc[mi][ni]);
  }

  // epilogue: C/D layout col=lane&15, row=(lane>>4)*4+reg
  #pragma unroll
  for (int mi = 0; mi < 4; mi++)
    #pragma unroll
    for (int ni = 0; ni < 4; ni++) {
      int col = n0 + wn + ni * 16 + lm;
      float bv = bias[col];
      #pragma unroll
      for (int r = 0; r < 4; r++) {
        int row = m0 + wm + mi * 16 + q * 4 + r;
        float v = acc[mi][ni][r] + bv;
        if (RELU) v = v > 0.f ? v : 0.f;
        C[(size_t)row * N + col] = (_Float16)v;
      }
    }
}

// ---------------------------------------------------------------------------
// Interaction: per sample, X = [h; emb_rows; zeros] (32x128 fp16), S = X*X^T,
// feat[b][0:128]=h, feat[b][128:506]=triu(S[0:27][0:27]), feat[b][506:512]=0.
// One wave per sample, 4 samples per block.
__global__ __launch_bounds__(256) void interact_kernel(
    const float* __restrict__ x, const float* __restrict__ emb,
    const _Float16* __restrict__ h, _Float16* __restrict__ feat) {
  constexpr int XS = 136;  // row stride in halfs (272B -> bank offset 4/row)
  __shared__ __align__(16) _Float16 X[4][32 * XS];
  __shared__ __align__(16) _Float16 F[4][512];
  __shared__ int IDX[4][26];
  int tid = threadIdx.x, wv = tid >> 6, lane = tid & 63;
  size_t b = (size_t)blockIdx.x * 4 + wv;

  if (lane < 26) IDX[wv][lane] = ((int)x[b * 39 + 13 + lane]) & VOCAB_MASK;
  {  // row 0 = h
    const _Float16* hp = h + b * 128;
    *(unsigned*)&X[wv][lane * 2] = *(const unsigned*)&hp[lane * 2];
  }
  #pragma unroll
  for (int r = 27; r < 32; r++) {  // zero pad rows
    X[wv][r * XS + lane] = (_Float16)0.f;
    X[wv][r * XS + lane + 64] = (_Float16)0.f;
  }
  __syncthreads();

  // gather 26 embedding rows (2 rows / iter, 32 lanes x float4 each)
  #pragma unroll
  for (int it = 0; it < 13; it++) {
    int r = 1 + it * 2 + (lane >> 5);
    int c = (lane & 31) * 4;
    int idx = IDX[wv][r - 1];
    float4 v = *(const float4*)(emb + (size_t)idx * 128 + c);
    _Float16* d = &X[wv][r * XS + c];
    d[0] = (_Float16)v.x; d[1] = (_Float16)v.y;
    d[2] = (_Float16)v.z; d[3] = (_Float16)v.w;
  }
  __syncthreads();

  // S = X * X^T via 2x2 tiles of 16x16x32, 4 k-steps
  f32x4 zero = {0.f, 0.f, 0.f, 0.f};
  f32x4 acc[2][2] = {{zero, zero}, {zero, zero}};
  int lm = lane & 15, q = lane >> 4;
  #pragma unroll
  for (int ks = 0; ks < 4; ks++) {
    half8 f0 = *(const half8*)&X[wv][(lm) * XS + ks * 32 + q * 8];
    half8 f1 = *(const half8*)&X[wv][(16 + lm) * XS + ks * 32 + q * 8];
    acc[0][0] = mfma_f16(f0, f0, acc[0][0]);
    acc[0][1] = mfma_f16(f0, f1, acc[0][1]);
    acc[1][0] = mfma_f16(f1, f0, acc[1][0]);
    acc[1][1] = mfma_f16(f1, f1, acc[1][1]);
  }

  // scatter upper-triangle entries into F, plus h copy and zero pad
  *(unsigned*)&F[wv][lane * 2] = *(const unsigned*)&X[wv][lane * 2];
  if (lane < 6) F[wv][506 + lane] = (_Float16)0.f;
  #pragma unroll
  for (int mt = 0; mt < 2; mt++)
    #pragma unroll
    for (int nt = 0; nt < 2; nt++)
      #pragma unroll
      for (int r = 0; r < 4; r++) {
        int i = mt * 16 + q * 4 + r;   // row
        int j = nt * 16 + lm;          // col
        if (i <= j && j < 27) {
          int off = 128 + i * 27 - i * (i - 1) / 2 + (j - i);
          F[wv][off] = (_Float16)acc[mt][nt][r];
        }
      }
  __syncthreads();

  *(float4*)(feat + b * 512 + lane * 8) = *(const float4*)&F[wv][lane * 8];
}

// ---------------------------------------------------------------------------
// Final layer: out[b] = A[b][:256] . w + bias  (fp32 weights, no relu)
__global__ __launch_bounds__(256) void final_gemv(
    const _Float16* __restrict__ A, const float* __restrict__ w,
    const float* __restrict__ bias, float* __restrict__ out) {
  int wv = threadIdx.x >> 6, lane = threadIdx.x & 63;
  size_t b = (size_t)blockIdx.x * 4 + wv;
  const _Float16* a = A + b * 256;
  float s = 0.f;
  #pragma unroll
  for (int j = 0; j < 4; j++)
    s += (float)a[lane + 64 * j] * w[lane + 64 * j];
  #pragma unroll
  for (int off = 32; off > 0; off >>= 1) s += __shfl_down(s, off, 64);
  if (lane == 0) out[b] = s + bias[0];
}

// ---------------------------------------------------------------------------
extern "C" void kernel_launch(void* const* d_in, const int* in_sizes, int n_in,
                              void* d_out, int out_size, void* d_ws, size_t ws_size,
                              hipStream_t stream) {
  const float* x   = (const float*)d_in[0];
  const float* emb = (const float*)d_in[1];
  const float* bw0 = (const float*)d_in[2];
  const float* bb0 = (const float*)d_in[3];
  const float* bw1 = (const float*)d_in[4];
  const float* bb1 = (const float*)d_in[5];
  const float* bw2 = (const float*)d_in[6];
  const float* bb2 = (const float*)d_in[7];
  const float* tw0 = (const float*)d_in[8];
  const float* tb0 = (const float*)d_in[9];
  const float* tw1 = (const float*)d_in[10];
  const float* tb1 = (const float*)d_in[11];
  const float* tw2 = (const float*)d_in[12];
  const float* tb2 = (const float*)d_in[13];
  const float* tw3 = (const float*)d_in[14];
  const float* tb3 = (const float*)d_in[15];
  const float* tw4 = (const float*)d_in[16];
  const float* tb4 = (const float*)d_in[17];
  float* out = (float*)d_out;

  char* ws = (char*)d_ws;
  _Float16* w0T = (_Float16*)ws;          // [512][32]
  _Float16* w1T = w0T + 512 * 32;         // [256][512]
  _Float16* w2T = w1T + 256 * 512;        // [128][256]
  _Float16* t0T = w2T + 128 * 256;        // [1024][512]
  _Float16* t1T = t0T + 1024 * 512;       // [1024][1024]
  _Float16* t2T = t1T + 1024 * 1024;      // [512][1024]
  _Float16* t3T = t2T + 512 * 1024;       // [256][512]  (ends < 5 MB)

  // two 32MB activation pools, ping-pong
  char* P1 = ws + (size_t)(5u << 20);
  char* P2 = ws + (size_t)(37u << 20);
  _Float16* dense16 = (_Float16*)P1;  // [B][32]
  _Float16* a1 = (_Float16*)P2;       // [B][512]
  _Float16* a2 = (_Float16*)P1;       // [B][256]
  _Float16* hb = (_Float16*)P2;       // [B][128]
  _Float16* ft = (_Float16*)P1;       // [B][512]
  _Float16* t0 = (_Float16*)P2;       // [B][1024]
  _Float16* t1 = (_Float16*)P1;       // [B][1024]
  _Float16* t2 = (_Float16*)P2;       // [B][512]
  _Float16* t3 = (_Float16*)P1;       // [B][256]

  dim3 tb(32, 8);
  transpose_to_f16<<<dim3(16, 1), tb, 0, stream>>>(bw0, w0T, 13, 512, 32);
  transpose_to_f16<<<dim3(8, 16), tb, 0, stream>>>(bw1, w1T, 512, 256, 512);
  transpose_to_f16<<<dim3(4, 8), tb, 0, stream>>>(bw2, w2T, 256, 128, 256);
  transpose_to_f16<<<dim3(32, 16), tb, 0, stream>>>(tw0, t0T, 506, 1024, 512);
  transpose_to_f16<<<dim3(32, 32), tb, 0, stream>>>(tw1, t1T, 1024, 1024, 1024);
  transpose_to_f16<<<dim3(16, 32), tb, 0, stream>>>(tw2, t2T, 1024, 512, 1024);
  transpose_to_f16<<<dim3(8, 16), tb, 0, stream>>>(tw3, t3T, 512, 256, 512);

  build_dense<<<BROWS * 32 / 256, 256, 0, stream>>>(x, dense16);

  gemm_bt<1><<<dim3(128, 4), 256, 0, stream>>>(dense16, w0T, bb0, a1, BROWS, 512, 32);
  gemm_bt<1><<<dim3(128, 2), 256, 0, stream>>>(a1, w1T, bb1, a2, BROWS, 256, 512);
  gemm_bt<1><<<dim3(128, 1), 256, 0, stream>>>(a2, w2T, bb2, hb, BROWS, 128, 256);

  interact_kernel<<<BROWS / 4, 256, 0, stream>>>(x, emb, hb, ft);

  gemm_bt<1><<<dim3(128, 8), 256, 0, stream>>>(ft, t0T, tb0, t0, BROWS, 1024, 512);
  gemm_bt<1><<<dim3(128, 8), 256, 0, stream>>>(t0, t1T, tb1, t1, BROWS, 1024, 1024);
  gemm_bt<1><<<dim3(128, 4), 256, 0, stream>>>(t1, t2T, tb2, t2, BROWS, 512, 1024);
  gemm_bt<1><<<dim3(128, 2), 256, 0, stream>>>(t2, t3T, tb3, t3, BROWS, 256, 512);

  final_gemv<<<BROWS / 4, 256, 0, stream>>>(t3, tw4, tb4, out);
}

// Round 2
// 838.142 us; speedup vs baseline: 1.0313x; 1.0313x over previous
//
#include <hip/hip_runtime.h>
#include <hip/hip_bf16.h>
#include <hip/hip_fp16.h>

// DLRM small: B=16384, VOCAB=2^20, EMBED=128
// bottom MLP 13->512->256->128 (relu), interaction (27x27 triu incl diag),
// top MLP 506->1024->1024->512->256->1 (relu except last).
//
// fp16 MFMA (16x16x32) for all matmuls, fp32 accumulate.
// R1: vectorized epilogue via LDS (64 scalar stores -> 8 dwordx4),
//     launch_bounds(256,3), fused init kernel (8 launches -> 1).

#define BROWS 16384
#define VOCAB_MASK 1048575

typedef __attribute__((ext_vector_type(8))) _Float16 half8;
typedef __attribute__((ext_vector_type(4))) float f32x4;

__device__ __forceinline__ void gld16(const void* g, void* l) {
  __builtin_amdgcn_global_load_lds(
      (const __attribute__((address_space(1))) void*)g,
      (__attribute__((address_space(3))) void*)l, 16, 0, 0);
}

__device__ __forceinline__ f32x4 mfma_f16(half8 a, half8 b, f32x4 c) {
  return __builtin_amdgcn_mfma_f32_16x16x32_f16(a, b, c, 0, 0, 0);
}

// ---------------------------------------------------------------------------
// Fused init: blockIdx.z 0..6 = weight transposes fp32[K][N] -> fp16[N][Kp],
// z=7 = build dense fp16 [B][32] from x fp32 [B][39].
__global__ __launch_bounds__(256) void init_fused(
    const float* __restrict__ x, _Float16* __restrict__ dense16,
    const float* s0, const float* s1, const float* s2, const float* s3,
    const float* s4, const float* s5, const float* s6,
    _Float16* d0, _Float16* d1, _Float16* d2, _Float16* d3,
    _Float16* d4, _Float16* d5, _Float16* d6) {
  __shared__ float tile[32][33];
  int z = blockIdx.z;
  int tx = threadIdx.x & 31, ty = threadIdx.x >> 5;  // 32 x 8
  if (z < 7) {
    const float* srcs[7] = {s0, s1, s2, s3, s4, s5, s6};
    _Float16* dsts[7] = {d0, d1, d2, d3, d4, d5, d6};
    const int Ks[7]  = {13, 512, 256, 506, 1024, 1024, 512};
    const int Ns[7]  = {512, 256, 128, 1024, 1024, 512, 256};
    const int Kps[7] = {32, 512, 256, 512, 1024, 1024, 512};
    int K = Ks[z], N = Ns[z], Kp = Kps[z];
    int kb = blockIdx.y * 32, nb = blockIdx.x * 32;
    if (kb >= Kp || nb >= N) return;
    const float* src = srcs[z];
    _Float16* dst = dsts[z];
    #pragma unroll
    for (int i = 0; i < 32; i += 8) {
      int k = kb + ty + i, n = nb + tx;
      tile[ty + i][tx] = (k < K && n < N) ? src[(size_t)k * N + n] : 0.f;
    }
    __syncthreads();
    #pragma unroll
    for (int i = 0; i < 32; i += 8) {
      int n = nb + ty + i, k = kb + tx;
      if (n < N && k < Kp) dst[(size_t)n * Kp + k] = (_Float16)tile[tx][ty + i];
    }
  } else {
    // build_dense: 1024 (x,y) blocks x 512 elems
    int id = blockIdx.y * 32 + blockIdx.x;
    int base = id * 512 + threadIdx.x * 2;
    #pragma unroll
    for (int j = 0; j < 2; j++) {
      int i = base + j;
      int b = i >> 5, c = i & 31;
      dense16[i] = (c < 13) ? (_Float16)x[(size_t)b * 39 + c] : (_Float16)0.f;
    }
  }
}

// ---------------------------------------------------------------------------
// GEMM: C[M][N] = act(A[M][K] * Bt[N][K]^T + bias), fp16 in/out, fp32 acc.
// m97 structure: 128x128 tile, BK=32, 4 waves, 4x4 16x16x32 fragments/wave.
// Epilogue staged through LDS for dwordx4 stores.
template <int RELU>
__global__ __launch_bounds__(256, 3) void gemm_bt(
    const _Float16* __restrict__ A, const _Float16* __restrict__ Bt,
    const float* __restrict__ bias, _Float16* __restrict__ C,
    int M, int N, int K) {
  // union: staging As[128*32]+Bs[128*32] (16 KB)  |  Cs[128][136] (34 KB)
  __shared__ __align__(16) char smem[128 * 136 * 2];
  _Float16* As = (_Float16*)smem;
  _Float16* Bs = As + 128 * 32;
  _Float16* Cs = (_Float16*)smem;
  constexpr int CS = 136;  // half stride; 272B/row -> 16B aligned

  int tid = threadIdx.x, lane = tid & 63;
  int wv = tid >> 6;
  int m0 = blockIdx.x * 128, n0 = blockIdx.y * 128;
  int wm = (wv & 1) * 64, wn = (wv >> 1) * 64;
  int lm = lane & 15, q = lane >> 4;

  f32x4 zero = {0.f, 0.f, 0.f, 0.f};
  f32x4 acc[4][4];
  #pragma unroll
  for (int i = 0; i < 4; i++)
    #pragma unroll
    for (int j = 0; j < 4; j++) acc[i][j] = zero;

  int c0 = tid, c1 = tid + 256;  // 16B chunks: row=c>>2, off=(c&3)*8
  int r0 = c0 >> 2, o0 = (c0 & 3) * 8;
  int r1 = c1 >> 2, o1 = (c1 & 3) * 8;

  for (int kk = 0; kk < K; kk += 32) {
    __syncthreads();  // previous iteration's readers done
    gld16(A + (size_t)(m0 + r0) * K + kk + o0, &As[c0 * 8]);
    gld16(A + (size_t)(m0 + r1) * K + kk + o1, &As[c1 * 8]);
    gld16(Bt + (size_t)(n0 + r0) * K + kk + o0, &Bs[c0 * 8]);
    gld16(Bt + (size_t)(n0 + r1) * K + kk + o1, &Bs[c1 * 8]);
    __syncthreads();  // vmcnt(0) drained -> tiles ready

    half8 af[4], bf[4];
    #pragma unroll
    for (int i = 0; i < 4; i++)
      af[i] = *(const half8*)&As[(wm + i * 16 + lm) * 32 + q * 8];
    #pragma unroll
    for (int i = 0; i < 4; i++)
      bf[i] = *(const half8*)&Bs[(wn + i * 16 + lm) * 32 + q * 8];
    #pragma unroll
    for (int mi = 0; mi < 4; mi++)
      #pragma unroll
      for (int ni = 0; ni < 4; ni++)
        acc[mi][ni] = mfma_f16(af[mi], bf[ni], acc[mi][ni]);
  }

  __syncthreads();  // all staging reads done before Cs overwrite

  // bias+relu into LDS fp16. C/D layout: col=lane&15, row=(lane>>4)*4+reg
  #pragma unroll
  for (int ni = 0; ni < 4; ni++) {
    int col_l = wn + ni * 16 + lm;
    float bv = bias[n0 + col_l];
    #pragma unroll
    for (int mi = 0; mi < 4; mi++)
      #pragma unroll
      for (int r = 0; r < 4; r++) {
        int row_l = wm + mi * 16 + q * 4 + r;
        float v = acc[mi][ni][r] + bv;
        if (RELU) v = v > 0.f ? v : 0.f;
        Cs[row_l * CS + col_l] = (_Float16)v;
      }
  }
  __syncthreads();

  // vectorized store: thread t -> row t>>1, 64 halfs at (t&1)*64
  {
    int row = tid >> 1, hoff = (tid & 1) * 64;
    const f32x4* src = (const f32x4*)&Cs[row * CS + hoff];
    f32x4* dst = (f32x4*)&C[(size_t)(m0 + row) * N + n0 + hoff];
    #pragma unroll
    for (int j = 0; j < 8; j++) dst[j] = src[j];
  }
}

// ---------------------------------------------------------------------------
// Interaction: per sample, X = [h; emb_rows; zeros] (32x128 fp16), S = X*X^T,
// feat[b][0:128]=h, feat[b][128:506]=triu(S[0:27][0:27]), feat[b][506:512]=0.
// One wave per sample, 4 samples per block.
__global__ __launch_bounds__(256) void interact_kernel(
    const float* __restrict__ x, const float* __restrict__ emb,
    const _Float16* __restrict__ h, _Float16* __restrict__ feat) {
  constexpr int XS = 136;
  __shared__ __align__(16) _Float16 X[4][32 * XS];
  __shared__ __align__(16) _Float16 F[4][512];
  __shared__ int IDX[4][26];
  int tid = threadIdx.x, wv = tid >> 6, lane = tid & 63;
  size_t b = (size_t)blockIdx.x * 4 + wv;

  if (lane < 26) IDX[wv][lane] = ((int)x[b * 39 + 13 + lane]) & VOCAB_MASK;
  {  // row 0 = h
    const _Float16* hp = h + b * 128;
    *(unsigned*)&X[wv][lane * 2] = *(const unsigned*)&hp[lane * 2];
  }
  #pragma unroll
  for (int r = 27; r < 32; r++) {  // zero pad rows
    X[wv][r * XS + lane] = (_Float16)0.f;
    X[wv][r * XS + lane + 64] = (_Float16)0.f;
  }
  __syncthreads();

  // gather 26 embedding rows (2 rows / iter, 32 lanes x float4 each)
  #pragma unroll
  for (int it = 0; it < 13; it++) {
    int r = 1 + it * 2 + (lane >> 5);
    int c = (lane & 31) * 4;
    int idx = IDX[wv][r - 1];
    float4 v = *(const float4*)(emb + (size_t)idx * 128 + c);
    _Float16* d = &X[wv][r * XS + c];
    d[0] = (_Float16)v.x; d[1] = (_Float16)v.y;
    d[2] = (_Float16)v.z; d[3] = (_Float16)v.w;
  }
  __syncthreads();

  // S = X * X^T via 2x2 tiles of 16x16x32, 4 k-steps
  f32x4 zero = {0.f, 0.f, 0.f, 0.f};
  f32x4 acc[2][2] = {{zero, zero}, {zero, zero}};
  int lm = lane & 15, q = lane >> 4;
  #pragma unroll
  for (int ks = 0; ks < 4; ks++) {
    half8 f0 = *(const half8*)&X[wv][(lm) * XS + ks * 32 + q * 8];
    half8 f1 = *(const half8*)&X[wv][(16 + lm) * XS + ks * 32 + q * 8];
    acc[0][0] = mfma_f16(f0, f0, acc[0][0]);
    acc[0][1] = mfma_f16(f0, f1, acc[0][1]);
    acc[1][0] = mfma_f16(f1, f0, acc[1][0]);
    acc[1][1] = mfma_f16(f1, f1, acc[1][1]);
  }

  // scatter upper-triangle entries into F, plus h copy and zero pad
  *(unsigned*)&F[wv][lane * 2] = *(const unsigned*)&X[wv][lane * 2];
  if (lane < 6) F[wv][506 + lane] = (_Float16)0.f;
  #pragma unroll
  for (int mt = 0; mt < 2; mt++)
    #pragma unroll
    for (int nt = 0; nt < 2; nt++)
      #pragma unroll
      for (int r = 0; r < 4; r++) {
        int i = mt * 16 + q * 4 + r;   // row
        int j = nt * 16 + lm;          // col
        if (i <= j && j < 27) {
          int off = 128 + i * 27 - i * (i - 1) / 2 + (j - i);
          F[wv][off] = (_Float16)acc[mt][nt][r];
        }
      }
  __syncthreads();

  *(float4*)(feat + b * 512 + lane * 8) = *(const float4*)&F[wv][lane * 8];
}

// ---------------------------------------------------------------------------
// Final layer: out[b] = A[b][:256] . w + bias  (fp32 weights, no relu)
__global__ __launch_bounds__(256) void final_gemv(
    const _Float16* __restrict__ A, const float* __restrict__ w,
    const float* __restrict__ bias, float* __restrict__ out) {
  int wv = threadIdx.x >> 6, lane = threadIdx.x & 63;
  size_t b = (size_t)blockIdx.x * 4 + wv;
  const _Float16* a = A + b * 256;
  float s = 0.f;
  #pragma unroll
  for (int j = 0; j < 4; j++)
    s += (float)a[lane + 64 * j] * w[lane + 64 * j];
  #pragma unroll
  for (int off = 32; off > 0; off >>= 1) s += __shfl_down(s, off, 64);
  if (lane == 0) out[b] = s + bias[0];
}

// ---------------------------------------------------------------------------
extern "C" void kernel_launch(void* const* d_in, const int* in_sizes, int n_in,
                              void* d_out, int out_size, void* d_ws, size_t ws_size,
                              hipStream_t stream) {
  const float* x   = (const float*)d_in[0];
  const float* emb = (const float*)d_in[1];
  const float* bw0 = (const float*)d_in[2];
  const float* bb0 = (const float*)d_in[3];
  const float* bw1 = (const float*)d_in[4];
  const float* bb1 = (const float*)d_in[5];
  const float* bw2 = (const float*)d_in[6];
  const float* bb2 = (const float*)d_in[7];
  const float* tw0 = (const float*)d_in[8];
  const float* tb0 = (const float*)d_in[9];
  const float* tw1 = (const float*)d_in[10];
  const float* tb1 = (const float*)d_in[11];
  const float* tw2 = (const float*)d_in[12];
  const float* tb2 = (const float*)d_in[13];
  const float* tw3 = (const float*)d_in[14];
  const float* tb3 = (const float*)d_in[15];
  const float* tw4 = (const float*)d_in[16];
  const float* tb4 = (const float*)d_in[17];
  float* out = (float*)d_out;

  char* ws = (char*)d_ws;
  _Float16* w0T = (_Float16*)ws;          // [512][32]
  _Float16* w1T = w0T + 512 * 32;         // [256][512]
  _Float16* w2T = w1T + 256 * 512;        // [128][256]
  _Float16* t0T = w2T + 128 * 256;        // [1024][512]
  _Float16* t1T = t0T + 1024 * 512;       // [1024][1024]
  _Float16* t2T = t1T + 1024 * 1024;      // [512][1024]
  _Float16* t3T = t2T + 512 * 1024;       // [256][512]  (ends < 5 MB)

  // two 32MB activation pools, ping-pong
  char* P1 = ws + (size_t)(5u << 20);
  char* P2 = ws + (size_t)(37u << 20);
  _Float16* dense16 = (_Float16*)P1;  // [B][32]
  _Float16* a1 = (_Float16*)P2;       // [B][512]
  _Float16* a2 = (_Float16*)P1;       // [B][256]
  _Float16* hb = (_Float16*)P2;       // [B][128]
  _Float16* ft = (_Float16*)P1;       // [B][512]
  _Float16* t0 = (_Float16*)P2;       // [B][1024]
  _Float16* t1 = (_Float16*)P1;       // [B][1024]
  _Float16* t2 = (_Float16*)P2;       // [B][512]
  _Float16* t3 = (_Float16*)P1;       // [B][256]

  init_fused<<<dim3(32, 32, 8), 256, 0, stream>>>(
      x, dense16, bw0, bw1, bw2, tw0, tw1, tw2, tw3,
      w0T, w1T, w2T, t0T, t1T, t2T, t3T);

  gemm_bt<1><<<dim3(128, 4), 256, 0, stream>>>(dense16, w0T, bb0, a1, BROWS, 512, 32);
  gemm_bt<1><<<dim3(128, 2), 256, 0, stream>>>(a1, w1T, bb1, a2, BROWS, 256, 512);
  gemm_bt<1><<<dim3(128, 1), 256, 0, stream>>>(a2, w2T, bb2, hb, BROWS, 128, 256);

  interact_kernel<<<BROWS / 4, 256, 0, stream>>>(x, emb, hb, ft);

  gemm_bt<1><<<dim3(128, 8), 256, 0, stream>>>(ft, t0T, tb0, t0, BROWS, 1024, 512);
  gemm_bt<1><<<dim3(128, 8), 256, 0, stream>>>(t0, t1T, tb1, t1, BROWS, 1024, 1024);
  gemm_bt<1><<<dim3(128, 4), 256, 0, stream>>>(t1, t2T, tb2, t2, BROWS, 512, 1024);
  gemm_bt<1><<<dim3(128, 2), 256, 0, stream>>>(t2, t3T, tb3, t3, BROWS, 256, 512);

  final_gemv<<<BROWS / 4, 256, 0, stream>>>(t3, tw4, tb4, out);
}

// Round 3
// 821.980 us; speedup vs baseline: 1.0516x; 1.0197x over previous
//
#include <hip/hip_runtime.h>
#include <hip/hip_bf16.h>
#include <hip/hip_fp16.h>

// DLRM small: B=16384, VOCAB=2^20, EMBED=128
// bottom MLP 13->512->256->128 (relu), interaction (27x27 triu incl diag),
// top MLP 506->1024->1024->512->256->1 (relu except last).
//
// fp16 MFMA (16x16x32), fp32 acc.
// R2: XCD-aware chunk swizzle (A-stripe read once per XCD, B L2-resident),
//     final 256->1 layer fused into T3 epilogue (shfl reduce + atomicAdd).

#define BROWS 16384
#define VOCAB_MASK 1048575

typedef __attribute__((ext_vector_type(8))) _Float16 half8;
typedef __attribute__((ext_vector_type(4))) float f32x4;

__device__ __forceinline__ void gld16(const void* g, void* l) {
  __builtin_amdgcn_global_load_lds(
      (const __attribute__((address_space(1))) void*)g,
      (__attribute__((address_space(3))) void*)l, 16, 0, 0);
}

__device__ __forceinline__ f32x4 mfma_f16(half8 a, half8 b, f32x4 c) {
  return __builtin_amdgcn_mfma_f32_16x16x32_f16(a, b, c, 0, 0, 0);
}

// ---------------------------------------------------------------------------
// Fused init: blockIdx.z 0..6 = weight transposes fp32[K][N] -> fp16[N][Kp],
// z=7 = build dense fp16 [B][32] from x fp32 [B][39].
__global__ __launch_bounds__(256) void init_fused(
    const float* __restrict__ x, _Float16* __restrict__ dense16,
    const float* s0, const float* s1, const float* s2, const float* s3,
    const float* s4, const float* s5, const float* s6,
    _Float16* d0, _Float16* d1, _Float16* d2, _Float16* d3,
    _Float16* d4, _Float16* d5, _Float16* d6) {
  __shared__ float tile[32][33];
  int z = blockIdx.z;
  int tx = threadIdx.x & 31, ty = threadIdx.x >> 5;  // 32 x 8
  if (z < 7) {
    const float* srcs[7] = {s0, s1, s2, s3, s4, s5, s6};
    _Float16* dsts[7] = {d0, d1, d2, d3, d4, d5, d6};
    const int Ks[7]  = {13, 512, 256, 506, 1024, 1024, 512};
    const int Ns[7]  = {512, 256, 128, 1024, 1024, 512, 256};
    const int Kps[7] = {32, 512, 256, 512, 1024, 1024, 512};
    int K = Ks[z], N = Ns[z], Kp = Kps[z];
    int kb = blockIdx.y * 32, nb = blockIdx.x * 32;
    if (kb >= Kp || nb >= N) return;
    const float* src = srcs[z];
    _Float16* dst = dsts[z];
    #pragma unroll
    for (int i = 0; i < 32; i += 8) {
      int k = kb + ty + i, n = nb + tx;
      tile[ty + i][tx] = (k < K && n < N) ? src[(size_t)k * N + n] : 0.f;
    }
    __syncthreads();
    #pragma unroll
    for (int i = 0; i < 32; i += 8) {
      int n = nb + ty + i, k = kb + tx;
      if (n < N && k < Kp) dst[(size_t)n * Kp + k] = (_Float16)tile[tx][ty + i];
    }
  } else {
    int id = blockIdx.y * 32 + blockIdx.x;
    int base = id * 512 + threadIdx.x * 2;
    #pragma unroll
    for (int j = 0; j < 2; j++) {
      int i = base + j;
      int b = i >> 5, c = i & 31;
      dense16[i] = (c < 13) ? (_Float16)x[(size_t)b * 39 + c] : (_Float16)0.f;
    }
  }
}

// ---------------------------------------------------------------------------
// GEMM: C = act(A[M][K] * Bt[N][K]^T + bias), fp16 in/out, fp32 acc.
// 128x128 tile, BK=32, 4 waves, 4x4 16x16x32 fragments/wave.
// 1-D grid with XCD chunk swizzle: chunk = 8 m-blocks x GY n-blocks;
// id%8 = m-stripe -> XCD, so each A-stripe is read by exactly one XCD.
// FUSE=1: instead of storing C, compute out[row] += sum relu(c)*w4 (atomic).
template <int RELU, int FUSE>
__global__ __launch_bounds__(256, 3) void gemm_bt(
    const _Float16* __restrict__ A, const _Float16* __restrict__ Bt,
    const float* __restrict__ bias, _Float16* __restrict__ C,
    int M, int N, int K, int GY,
    const float* __restrict__ w4, const float* __restrict__ b4,
    float* __restrict__ out) {
  __shared__ __align__(16) char smem[128 * 136 * 2];
  _Float16* As = (_Float16*)smem;
  _Float16* Bs = As + 128 * 32;
  _Float16* Cs = (_Float16*)smem;
  constexpr int CS = 136;

  int id = blockIdx.x;
  int cs = GY * 8;
  int c = id / cs, r = id - c * cs;
  int m0 = (c * 8 + (r & 7)) * 128;
  int n0 = (r >> 3) * 128;

  int tid = threadIdx.x, lane = tid & 63;
  int wv = tid >> 6;
  int wm = (wv & 1) * 64, wn = (wv >> 1) * 64;
  int lm = lane & 15, q = lane >> 4;

  f32x4 zero = {0.f, 0.f, 0.f, 0.f};
  f32x4 acc[4][4];
  #pragma unroll
  for (int i = 0; i < 4; i++)
    #pragma unroll
    for (int j = 0; j < 4; j++) acc[i][j] = zero;

  int c0 = tid, c1 = tid + 256;  // 16B chunks: row=c>>2, off=(c&3)*8
  int r0 = c0 >> 2, o0 = (c0 & 3) * 8;
  int r1 = c1 >> 2, o1 = (c1 & 3) * 8;

  for (int kk = 0; kk < K; kk += 32) {
    __syncthreads();
    gld16(A + (size_t)(m0 + r0) * K + kk + o0, &As[c0 * 8]);
    gld16(A + (size_t)(m0 + r1) * K + kk + o1, &As[c1 * 8]);
    gld16(Bt + (size_t)(n0 + r0) * K + kk + o0, &Bs[c0 * 8]);
    gld16(Bt + (size_t)(n0 + r1) * K + kk + o1, &Bs[c1 * 8]);
    __syncthreads();

    half8 af[4], bf[4];
    #pragma unroll
    for (int i = 0; i < 4; i++)
      af[i] = *(const half8*)&As[(wm + i * 16 + lm) * 32 + q * 8];
    #pragma unroll
    for (int i = 0; i < 4; i++)
      bf[i] = *(const half8*)&Bs[(wn + i * 16 + lm) * 32 + q * 8];
    #pragma unroll
    for (int mi = 0; mi < 4; mi++)
      #pragma unroll
      for (int ni = 0; ni < 4; ni++)
        acc[mi][ni] = mfma_f16(af[mi], bf[ni], acc[mi][ni]);
  }

  if (!FUSE) {
    __syncthreads();
    // bias+relu into LDS fp16. C/D layout: col=lane&15, row=(lane>>4)*4+reg
    #pragma unroll
    for (int ni = 0; ni < 4; ni++) {
      int col_l = wn + ni * 16 + lm;
      float bv = bias[n0 + col_l];
      #pragma unroll
      for (int mi = 0; mi < 4; mi++)
        #pragma unroll
        for (int rr = 0; rr < 4; rr++) {
          int row_l = wm + mi * 16 + q * 4 + rr;
          float v = acc[mi][ni][rr] + bv;
          if (RELU) v = v > 0.f ? v : 0.f;
          Cs[row_l * CS + col_l] = (_Float16)v;
        }
    }
    __syncthreads();
    int row = tid >> 1, hoff = (tid & 1) * 64;
    const f32x4* src = (const f32x4*)&Cs[row * CS + hoff];
    f32x4* dst = (f32x4*)&C[(size_t)(m0 + row) * N + n0 + hoff];
    #pragma unroll
    for (int j = 0; j < 8; j++) dst[j] = src[j];
  } else {
    // fused last layer: out[row] += sum_col relu(acc+bias)*w4[col] (+ b4 once)
    float part[4][4];
    #pragma unroll
    for (int mi = 0; mi < 4; mi++)
      #pragma unroll
      for (int rr = 0; rr < 4; rr++) part[mi][rr] = 0.f;
    #pragma unroll
    for (int ni = 0; ni < 4; ni++) {
      int col = n0 + wn + ni * 16 + lm;
      float bv = bias[col], wv4 = w4[col];
      #pragma unroll
      for (int mi = 0; mi < 4; mi++)
        #pragma unroll
        for (int rr = 0; rr < 4; rr++) {
          float v = acc[mi][ni][rr] + bv;
          v = v > 0.f ? v : 0.f;
          part[mi][rr] += v * wv4;
        }
    }
    #pragma unroll
    for (int mi = 0; mi < 4; mi++)
      #pragma unroll
      for (int rr = 0; rr < 4; rr++) {
        float v = part[mi][rr];
        v += __shfl_xor(v, 1);
        v += __shfl_xor(v, 2);
        v += __shfl_xor(v, 4);
        v += __shfl_xor(v, 8);
        part[mi][rr] = v;
      }
    if (lm == 0) {
      float bout = (n0 == 0 && wn == 0) ? b4[0] : 0.f;
      #pragma unroll
      for (int mi = 0; mi < 4; mi++)
        #pragma unroll
        for (int rr = 0; rr < 4; rr++)
          atomicAdd(&out[m0 + wm + mi * 16 + q * 4 + rr],
                    part[mi][rr] + bout);
    }
  }
}

// ---------------------------------------------------------------------------
// Interaction: per sample, X = [h; emb_rows; zeros] (32x128 fp16), S = X*X^T,
// feat = [h | triu(S[0:27][0:27]) | 0 pad to 512]. One wave per sample.
__global__ __launch_bounds__(256) void interact_kernel(
    const float* __restrict__ x, const float* __restrict__ emb,
    const _Float16* __restrict__ h, _Float16* __restrict__ feat) {
  constexpr int XS = 136;
  __shared__ __align__(16) _Float16 X[4][32 * XS];
  __shared__ __align__(16) _Float16 F[4][512];
  __shared__ int IDX[4][26];
  int tid = threadIdx.x, wv = tid >> 6, lane = tid & 63;
  size_t b = (size_t)blockIdx.x * 4 + wv;

  if (lane < 26) IDX[wv][lane] = ((int)x[b * 39 + 13 + lane]) & VOCAB_MASK;
  {
    const _Float16* hp = h + b * 128;
    *(unsigned*)&X[wv][lane * 2] = *(const unsigned*)&hp[lane * 2];
  }
  #pragma unroll
  for (int r = 27; r < 32; r++) {
    X[wv][r * XS + lane] = (_Float16)0.f;
    X[wv][r * XS + lane + 64] = (_Float16)0.f;
  }
  __syncthreads();

  #pragma unroll
  for (int it = 0; it < 13; it++) {
    int r = 1 + it * 2 + (lane >> 5);
    int c = (lane & 31) * 4;
    int idx = IDX[wv][r - 1];
    float4 v = *(const float4*)(emb + (size_t)idx * 128 + c);
    _Float16* d = &X[wv][r * XS + c];
    d[0] = (_Float16)v.x; d[1] = (_Float16)v.y;
    d[2] = (_Float16)v.z; d[3] = (_Float16)v.w;
  }
  __syncthreads();

  f32x4 zero = {0.f, 0.f, 0.f, 0.f};
  f32x4 acc[2][2] = {{zero, zero}, {zero, zero}};
  int lm = lane & 15, q = lane >> 4;
  #pragma unroll
  for (int ks = 0; ks < 4; ks++) {
    half8 f0 = *(const half8*)&X[wv][(lm) * XS + ks * 32 + q * 8];
    half8 f1 = *(const half8*)&X[wv][(16 + lm) * XS + ks * 32 + q * 8];
    acc[0][0] = mfma_f16(f0, f0, acc[0][0]);
    acc[0][1] = mfma_f16(f0, f1, acc[0][1]);
    acc[1][0] = mfma_f16(f1, f0, acc[1][0]);
    acc[1][1] = mfma_f16(f1, f1, acc[1][1]);
  }

  *(unsigned*)&F[wv][lane * 2] = *(const unsigned*)&X[wv][lane * 2];
  if (lane < 6) F[wv][506 + lane] = (_Float16)0.f;
  #pragma unroll
  for (int mt = 0; mt < 2; mt++)
    #pragma unroll
    for (int nt = 0; nt < 2; nt++)
      #pragma unroll
      for (int r = 0; r < 4; r++) {
        int i = mt * 16 + q * 4 + r;
        int j = nt * 16 + lm;
        if (i <= j && j < 27) {
          int off = 128 + i * 27 - i * (i - 1) / 2 + (j - i);
          F[wv][off] = (_Float16)acc[mt][nt][r];
        }
      }
  __syncthreads();

  *(float4*)(feat + b * 512 + lane * 8) = *(const float4*)&F[wv][lane * 8];
}

// ---------------------------------------------------------------------------
extern "C" void kernel_launch(void* const* d_in, const int* in_sizes, int n_in,
                              void* d_out, int out_size, void* d_ws, size_t ws_size,
                              hipStream_t stream) {
  const float* x   = (const float*)d_in[0];
  const float* emb = (const float*)d_in[1];
  const float* bw0 = (const float*)d_in[2];
  const float* bb0 = (const float*)d_in[3];
  const float* bw1 = (const float*)d_in[4];
  const float* bb1 = (const float*)d_in[5];
  const float* bw2 = (const float*)d_in[6];
  const float* bb2 = (const float*)d_in[7];
  const float* tw0 = (const float*)d_in[8];
  const float* tb0 = (const float*)d_in[9];
  const float* tw1 = (const float*)d_in[10];
  const float* tb1 = (const float*)d_in[11];
  const float* tw2 = (const float*)d_in[12];
  const float* tb2 = (const float*)d_in[13];
  const float* tw3 = (const float*)d_in[14];
  const float* tb3 = (const float*)d_in[15];
  const float* tw4 = (const float*)d_in[16];
  const float* tb4 = (const float*)d_in[17];
  float* out = (float*)d_out;

  char* ws = (char*)d_ws;
  _Float16* w0T = (_Float16*)ws;          // [512][32]
  _Float16* w1T = w0T + 512 * 32;         // [256][512]
  _Float16* w2T = w1T + 256 * 512;        // [128][256]
  _Float16* t0T = w2T + 128 * 256;        // [1024][512]
  _Float16* t1T = t0T + 1024 * 512;       // [1024][1024]
  _Float16* t2T = t1T + 1024 * 1024;      // [512][1024]
  _Float16* t3T = t2T + 512 * 1024;       // [256][512]

  char* P1 = ws + (size_t)(5u << 20);
  char* P2 = ws + (size_t)(37u << 20);
  _Float16* dense16 = (_Float16*)P1;  // [B][32]
  _Float16* a1 = (_Float16*)P2;       // [B][512]
  _Float16* a2 = (_Float16*)P1;       // [B][256]
  _Float16* hb = (_Float16*)P2;       // [B][128]
  _Float16* ft = (_Float16*)P1;       // [B][512]
  _Float16* t0 = (_Float16*)P2;       // [B][1024]
  _Float16* t1 = (_Float16*)P1;       // [B][1024]
  _Float16* t2 = (_Float16*)P2;       // [B][512]

  hipMemsetAsync(d_out, 0, (size_t)out_size * sizeof(float), stream);

  init_fused<<<dim3(32, 32, 8), 256, 0, stream>>>(
      x, dense16, bw0, bw1, bw2, tw0, tw1, tw2, tw3,
      w0T, w1T, w2T, t0T, t1T, t2T, t3T);

  gemm_bt<1, 0><<<128 * 4, 256, 0, stream>>>(dense16, w0T, bb0, a1,
      BROWS, 512, 32, 4, nullptr, nullptr, nullptr);
  gemm_bt<1, 0><<<128 * 2, 256, 0, stream>>>(a1, w1T, bb1, a2,
      BROWS, 256, 512, 2, nullptr, nullptr, nullptr);
  gemm_bt<1, 0><<<128 * 1, 256, 0, stream>>>(a2, w2T, bb2, hb,
      BROWS, 128, 256, 1, nullptr, nullptr, nullptr);

  interact_kernel<<<BROWS / 4, 256, 0, stream>>>(x, emb, hb, ft);

  gemm_bt<1, 0><<<128 * 8, 256, 0, stream>>>(ft, t0T, tb0, t0,
      BROWS, 1024, 512, 8, nullptr, nullptr, nullptr);
  gemm_bt<1, 0><<<128 * 8, 256, 0, stream>>>(t0, t1T, tb1, t1,
      BROWS, 1024, 1024, 8, nullptr, nullptr, nullptr);
  gemm_bt<1, 0><<<128 * 4, 256, 0, stream>>>(t1, t2T, tb2, t2,
      BROWS, 512, 1024, 4, nullptr, nullptr, nullptr);
  gemm_bt<1, 1><<<128 * 2, 256, 0, stream>>>(t2, t3T, tb3, nullptr,
      BROWS, 256, 512, 2, tw4, tb4, out);
}